// Round 16
// baseline (241.607 us; speedup 1.0000x reference)
//
#include <hip/hip_runtime.h>

#define N_NODES 100000
#define N_EDGES 1600000
#define D 128
#define GEMM_GRID 6250      // one block per 16-row tile
#define TILE_ROWS 16
#define BK_NODES 256        // nodes per bucket
#define N_BUCKETS 391       // ceil(N_NODES / BK_NODES)
#define BKT_CAP 5120        // per-bucket slot capacity (mean 4092, std 64 -> 16 sigma)
#define SC_BLOCKS 128
#define EPB 12500           // edges per scatter block (N_EDGES / SC_BLOCKS)
#define DS_BLOCKS 25
#define NPB 4000            // nodes per degree-sort block
#define NBINS 32

typedef _Float16 f16;
typedef _Float16 f16x8 __attribute__((ext_vector_type(8)));
typedef _Float16 f16x2 __attribute__((ext_vector_type(2)));
typedef float f32x2 __attribute__((ext_vector_type(2)));
typedef float f32x4 __attribute__((ext_vector_type(4)));

// bf16 bit pattern of w in [0,1] fits in 15 bits (max 0x3F80 = 1.0), RNE-ish
__device__ __forceinline__ unsigned bf16bits(float x) {
    unsigned u = __float_as_uint(x);
    return ((u + 0x8000u) >> 16) & 0x7fffu;
}

// ---------------- CSR build (bucket-based, no per-node global atomics) ----------------

__global__ __launch_bounds__(256) void bucket_scatter(const int* __restrict__ src,
                                                      const int* __restrict__ dst,
                                                      const float* __restrict__ w,
                                                      int* __restrict__ bcur,
                                                      int2* __restrict__ bkt) {
    __shared__ int hist[N_BUCKETS];
    __shared__ int base[N_BUCKETS];
    int tid = threadIdx.x;
    int v0  = blockIdx.x * (EPB / 4);        // int4-chunk base
    const int4*   dst4 = (const int4*)dst;
    const int4*   src4 = (const int4*)src;
    const float4* w4   = (const float4*)w;

    for (int b = tid; b < N_BUCKETS; b += 256) hist[b] = 0;
    __syncthreads();

    // phase A: count buckets (vectorized dst reads)
    for (int v = tid; v < EPB / 4; v += 256) {
        int4 d = dst4[v0 + v];
        atomicAdd(&hist[d.x >> 8], 1);
        atomicAdd(&hist[d.y >> 8], 1);
        atomicAdd(&hist[d.z >> 8], 1);
        atomicAdd(&hist[d.w >> 8], 1);
    }
    __syncthreads();

    // phase B: reserve within-bucket ranges (bcur starts at 0)
    for (int b = tid; b < N_BUCKETS; b += 256) {
        int c = hist[b];
        base[b] = b * BKT_CAP + ((c > 0) ? atomicAdd(&bcur[b], c) : 0);
        hist[b] = 0;
    }
    __syncthreads();

    // phase C: place edges densely inside reserved ranges (meta = dst<<15 | bf16(w))
    for (int v = tid; v < EPB / 4; v += 256) {
        int4   d = dst4[v0 + v];
        int4   s = src4[v0 + v];
        float4 f = w4[v0 + v];
        {
            int p = base[d.x >> 8] + atomicAdd(&hist[d.x >> 8], 1);
            bkt[p] = make_int2(s.x, (int)(((unsigned)d.x << 15) | bf16bits(f.x)));
        }
        {
            int p = base[d.y >> 8] + atomicAdd(&hist[d.y >> 8], 1);
            bkt[p] = make_int2(s.y, (int)(((unsigned)d.y << 15) | bf16bits(f.y)));
        }
        {
            int p = base[d.z >> 8] + atomicAdd(&hist[d.z >> 8], 1);
            bkt[p] = make_int2(s.z, (int)(((unsigned)d.z << 15) | bf16bits(f.z)));
        }
        {
            int p = base[d.w >> 8] + atomicAdd(&hist[d.w >> 8], 1);
            bkt[p] = make_int2(s.w, (int)(((unsigned)d.w << 15) | bf16bits(f.w)));
        }
    }
}

// exclusive scan over the 391 bucket counts -> bucket CSR bases (one block)
__global__ __launch_bounds__(512) void bucket_scan(const int* __restrict__ bcnt,
                                                   int* __restrict__ bbase) {
    __shared__ int sc[512];
    int tid = threadIdx.x;
    int v = (tid < N_BUCKETS) ? bcnt[tid] : 0;
    sc[tid] = v;
    __syncthreads();
    for (int off = 1; off < 512; off <<= 1) {
        int t = (tid >= off) ? sc[tid - off] : 0;
        __syncthreads();
        sc[tid] += t;
        __syncthreads();
    }
    if (tid < N_BUCKETS) bbase[tid] = sc[tid] - v;
}

// pass 2: one block per bucket. LDS node histogram + block scan -> row_ptr AND
// final csr placement. csr[p] = (src << 15) | bf16(w).
__global__ __launch_bounds__(256) void bucket_finalize(const int* __restrict__ bcnt,
                                                       const int* __restrict__ bbase,
                                                       const int2* __restrict__ bkt,
                                                       unsigned* __restrict__ csr,
                                                       int* __restrict__ row_ptr) {
    __shared__ int ncnt[BK_NODES];
    __shared__ int noff[BK_NODES];
    __shared__ int sc[BK_NODES];
    int tid   = threadIdx.x;
    int b     = blockIdx.x;
    int node0 = b * BK_NODES;
    int cnt   = bcnt[b];
    int base  = bbase[b];
    int e0    = b * BKT_CAP;

    ncnt[tid] = 0;
    __syncthreads();
    for (int i = tid; i < cnt; i += 256) {
        int local = (int)((unsigned)bkt[e0 + i].y >> 15) - node0;
        atomicAdd(&ncnt[local], 1);
    }
    __syncthreads();
    int s = ncnt[tid];
    sc[tid] = s;
    __syncthreads();
    for (int off = 1; off < 256; off <<= 1) {
        int t = (tid >= off) ? sc[tid - off] : 0;
        __syncthreads();
        sc[tid] += t;
        __syncthreads();
    }
    noff[tid] = sc[tid] - s;
    ncnt[tid] = 0;   // reuse as placement cursor
    {
        int nN = N_NODES - node0; if (nN > BK_NODES) nN = BK_NODES;
        if (tid < nN) row_ptr[node0 + tid] = base + noff[tid];
        if (b == N_BUCKETS - 1 && tid == 0) row_ptr[N_NODES] = N_EDGES;
    }
    __syncthreads();
    for (int i = tid; i < cnt; i += 256) {
        int2 t = bkt[e0 + i];
        unsigned meta = (unsigned)t.y;
        int local = (int)(meta >> 15) - node0;
        int p = base + noff[local] + atomicAdd(&ncnt[local], 1);
        csr[p] = ((unsigned)t.x << 15) | (meta & 0x7fffu);
    }
}

// ---------------- degree-equalized permutation (counting sort by degree) ----------------
// Blocks of 16 consecutive perm entries get IDENTICAL degree (width-1 bins) ->
// no divergent edge-loop, no barrier skew in fused_layer.

__global__ __launch_bounds__(1024) void degree_hist(const int* __restrict__ row_ptr,
                                                    int* __restrict__ ghist) {
    __shared__ int hist[NBINS];
    int tid = threadIdx.x;
    if (tid < NBINS) hist[tid] = 0;
    __syncthreads();
    int n0 = blockIdx.x * NPB;
    for (int i = tid; i < NPB; i += 1024) {
        int node = n0 + i;
        int deg = row_ptr[node + 1] - row_ptr[node];
        int bin = deg < NBINS - 1 ? deg : NBINS - 1;
        atomicAdd(&hist[bin], 1);
    }
    __syncthreads();
    if (tid < NBINS && hist[tid] > 0) atomicAdd(&ghist[tid], hist[tid]);
}

__global__ void bin_scan(const int* __restrict__ ghist, int* __restrict__ gcur) {
    if (threadIdx.x == 0 && blockIdx.x == 0) {
        int run = 0;
        for (int b = 0; b < NBINS; ++b) { gcur[b] = run; run += ghist[b]; }
    }
}

__global__ __launch_bounds__(1024) void degree_place(const int* __restrict__ row_ptr,
                                                     int* __restrict__ gcur,
                                                     int* __restrict__ perm) {
    __shared__ int hist[NBINS];
    __shared__ int base[NBINS];
    int tid = threadIdx.x;
    if (tid < NBINS) hist[tid] = 0;
    __syncthreads();
    int n0 = blockIdx.x * NPB;
    for (int i = tid; i < NPB; i += 1024) {
        int node = n0 + i;
        int deg = row_ptr[node + 1] - row_ptr[node];
        int bin = deg < NBINS - 1 ? deg : NBINS - 1;
        atomicAdd(&hist[bin], 1);
    }
    __syncthreads();
    if (tid < NBINS) {
        int c = hist[tid];
        base[tid] = (c > 0) ? atomicAdd(&gcur[tid], c) : 0;
        hist[tid] = 0;
    }
    __syncthreads();
    for (int i = tid; i < NPB; i += 1024) {
        int node = n0 + i;
        int deg = row_ptr[node + 1] - row_ptr[node];
        int bin = deg < NBINS - 1 ? deg : NBINS - 1;
        int p = base[bin] + atomicAdd(&hist[bin], 1);
        perm[p] = node;
    }
}

// ---------------- fp32 -> f16 + fp8 convert (x only, once) ----------------

__global__ __launch_bounds__(256) void cvt_x(const float* __restrict__ in,
                                             f16* __restrict__ out16,
                                             unsigned char* __restrict__ out8) {
    int i = blockIdx.x * 256 + threadIdx.x;   // grid 6250: 8 elems/thread
    const float4* in4 = (const float4*)in;
    float4 a = in4[i * 2], b = in4[i * 2 + 1];
    f16x8 v;
    v[0] = (f16)a.x; v[1] = (f16)a.y; v[2] = (f16)a.z; v[3] = (f16)a.w;
    v[4] = (f16)b.x; v[5] = (f16)b.y; v[6] = (f16)b.z; v[7] = (f16)b.w;
    ((f16x8*)out16)[i] = v;
    uint2 p8;
    int r = __builtin_amdgcn_cvt_pk_fp8_f32(a.x, a.y, 0, false);
    r     = __builtin_amdgcn_cvt_pk_fp8_f32(a.z, a.w, r, true);
    p8.x = (unsigned)r;
    r     = __builtin_amdgcn_cvt_pk_fp8_f32(b.x, b.y, 0, false);
    r     = __builtin_amdgcn_cvt_pk_fp8_f32(b.z, b.w, r, true);
    p8.y = (unsigned)r;
    ((uint2*)out8)[i] = p8;
}

// ---------------- weight pack: B-fragment layout, f16 ----------------
// Bp element ((ks*8 + ct)*64 + lane)*8 + e = W[j][k] with
// j = ct*16 + (lane&15), k = ks*32 + (lane>>4)*8 + e  (k<128 -> Wrel, else Wroot)

__global__ __launch_bounds__(256) void pack_weights(const float* __restrict__ Wrel,
                                                    const float* __restrict__ Wroot,
                                                    f16* __restrict__ Bp) {
    int idx = blockIdx.x * 256 + threadIdx.x;   // 32768 total -> 128 blocks
    int e = idx & 7, lane = (idx >> 3) & 63, ct = (idx >> 9) & 7, ks = idx >> 12;
    int j = ct * 16 + (lane & 15);
    int k = ks * 32 + (lane >> 4) * 8 + e;
    float w = (k < D) ? Wrel[j * D + k] : Wroot[j * D + (k - D)];
    Bp[idx] = (f16)w;
}

// ---------------- FUSED layer: quad-per-node fp8 aggregate + MFMA GEMM ----------------
// 16-row tiles over PERMUTED nodes: block b handles perm[b*16..+16), all same
// degree -> no divergence, no barrier skew. Phase 1: each 16-lane QUAD owns one
// node; lane covers 8 fp8 channels. 8-batch unroll, csr prefetch, f32 accum,
// f16x8 into swizzled LDS. Phase 2: wave wid computes 16 rows x cols
// [wid*32,+32), B streamed. Epilogue scatters rows to true node ids.
// FINAL=0: f16 out + fp8 out + ReLU.  FINAL=1: fp32 out only.

#define FMA8(CWV)                                                              \
    {                                                                          \
        float w = __uint_as_float(((CWV) & 0x7fffu) << 16);                    \
        f32x2 c0 = __builtin_amdgcn_cvt_pk_f32_fp8((int)rv[j].x, false);       \
        f32x2 c1 = __builtin_amdgcn_cvt_pk_f32_fp8((int)rv[j].x, true);        \
        f32x2 c2 = __builtin_amdgcn_cvt_pk_f32_fp8((int)rv[j].y, false);       \
        f32x2 c3 = __builtin_amdgcn_cvt_pk_f32_fp8((int)rv[j].y, true);        \
        a0 = fmaf(w, c0.x, a0); a1 = fmaf(w, c0.y, a1);                        \
        a2 = fmaf(w, c1.x, a2); a3 = fmaf(w, c1.y, a3);                        \
        a4 = fmaf(w, c2.x, a4); a5 = fmaf(w, c2.y, a5);                        \
        a6 = fmaf(w, c3.x, a6); a7 = fmaf(w, c3.y, a7);                        \
    }

template <int FINAL>
__global__ __launch_bounds__(256) void fused_layer(const f16* __restrict__ h,
                                                   const unsigned char* __restrict__ h8,
                                                   const int* __restrict__ row_ptr,
                                                   const unsigned* __restrict__ csr,
                                                   const int* __restrict__ perm,
                                                   const f16x8* __restrict__ Bp,
                                                   const float* __restrict__ bias,
                                                   void* __restrict__ outp,
                                                   unsigned char* __restrict__ outp8) {
    __shared__ f16 sA[TILE_ROWS * 256];   // 8 KB: [row][k] k<128 agg, k>=128 h (XOR swz)
    int tid  = threadIdx.x;
    int lane = tid & 63;
    int wid  = tid >> 6;
    int node0 = blockIdx.x * TILE_ROWS;
    const uint4* h16 = (const uint4*)h;

    // ---- phase 1a: quad-per-node aggregation (fp8 rows, 8 B/lane) ----
    int quad = lane >> 4;             // 0..3
    int ql   = lane & 15;
    unsigned qoff = (unsigned)ql * 8u;   // byte offset into 128B fp8 row

    {
        int row  = wid * 4 + quad;    // 0..15: one node per quad
        int node = perm[node0 + row]; // quad-broadcast load
        int beg = row_ptr[node], end = row_ptr[node + 1];

        float a0 = 0.f, a1 = 0.f, a2 = 0.f, a3 = 0.f;
        float a4 = 0.f, a5 = 0.f, a6 = 0.f, a7 = 0.f;

        int e = beg;
        unsigned cw[8];
        if (e + 8 <= end) {
#pragma unroll
            for (int j = 0; j < 8; ++j) cw[j] = csr[e + j];   // quad-broadcast lines
        }
        while (e + 8 <= end) {
            uint2 rv[8];
            __builtin_amdgcn_sched_barrier(0);
#pragma unroll
            for (int j = 0; j < 8; ++j) {
                unsigned off = ((cw[j] >> 8) & 0xFFFFFF80u) | qoff;  // (src)*128 | ql*8
                rv[j] = *(const uint2*)(h8 + off);                   // 4 edges / wave inst
            }
            unsigned cwn[8];
            bool more = (e + 16 <= end);
            if (more) {   // prefetch next batch's csr words under the gathers
#pragma unroll
                for (int j = 0; j < 8; ++j) cwn[j] = csr[e + 8 + j];
            }
            __builtin_amdgcn_sched_barrier(0);
#pragma unroll
            for (int j = 0; j < 8; ++j) FMA8(cw[j]);
            if (more) {
#pragma unroll
                for (int j = 0; j < 8; ++j) cw[j] = cwn[j];
            }
            e += 8;
        }
        if (e < end) {   // clamped tail batch (1..7 edges), w=0 for dead j
            int rem = end - e;
            int em1 = end - 1;
            unsigned sm[8];
            uint2 rv[8];
#pragma unroll
            for (int j = 0; j < 8; ++j) {
                int idx = e + j; idx = idx < em1 ? idx : em1;
                unsigned c = csr[idx];
                sm[j] = (j < rem) ? c : 0u;
            }
            __builtin_amdgcn_sched_barrier(0);
#pragma unroll
            for (int j = 0; j < 8; ++j) {
                unsigned off = ((sm[j] >> 8) & 0xFFFFFF80u) | qoff;
                rv[j] = *(const uint2*)(h8 + off);
            }
            __builtin_amdgcn_sched_barrier(0);
#pragma unroll
            for (int j = 0; j < 8; ++j) FMA8(sm[j]);
        }
        f16x8 ov;
        ov[0] = (f16)a0; ov[1] = (f16)a1; ov[2] = (f16)a2; ov[3] = (f16)a3;
        ov[4] = (f16)a4; ov[5] = (f16)a5; ov[6] = (f16)a6; ov[7] = (f16)a7;
        int o = (row * 256 + ql * 8) ^ ((row & 7) << 3);
        *(f16x8*)&sA[o] = ov;
    }

    // ---- phase 1b: stage f16 h rows (true node ids) into cols 128-255 ----
    {
        int r = tid >> 4, c8 = (tid & 15) + 16;
        int nr = perm[node0 + r];
        int o = (r * 256 + c8 * 8) ^ ((r & 7) << 3);
        *(uint4*)&sA[o] = h16[(size_t)nr * 16 + (c8 - 16)];
    }
    __syncthreads();

    // ---- phase 2: MFMA — wave wid: all 16 rows x cols [wid*32,+32) ----
    float bv[2];
#pragma unroll
    for (int c = 0; c < 2; ++c) bv[c] = bias[wid * 32 + c * 16 + (lane & 15)];

    f32x4 acc[2] = {f32x4{0,0,0,0}, f32x4{0,0,0,0}};
    int arow = lane & 15;
    int kg   = (lane >> 4) * 8;

    f16x8 b0 = Bp[(0 * 8 + wid * 2 + 0) * 64 + lane];
    f16x8 b1 = Bp[(0 * 8 + wid * 2 + 1) * 64 + lane];
#pragma unroll 1
    for (int ks = 0; ks < 8; ++ks) {
        f16x8 n0, n1;
        if (ks < 7) {   // 1-deep pipeline: issue next B-frags before MFMA
            n0 = Bp[((ks + 1) * 8 + wid * 2 + 0) * 64 + lane];
            n1 = Bp[((ks + 1) * 8 + wid * 2 + 1) * 64 + lane];
        }
        int o = (arow * 256 + ks * 32 + kg) ^ ((arow & 7) << 3);
        f16x8 afrag = *(const f16x8*)&sA[o];
        acc[0] = __builtin_amdgcn_mfma_f32_16x16x32_f16(afrag, b0, acc[0], 0, 0, 0);
        acc[1] = __builtin_amdgcn_mfma_f32_16x16x32_f16(afrag, b1, acc[1], 0, 0, 0);
        b0 = n0; b1 = n1;
    }

    // epilogue: bias (+relu), scatter rows to true node ids
    int prow[4];
#pragma unroll
    for (int r = 0; r < 4; ++r) prow[r] = perm[node0 + (lane >> 4) * 4 + r];
#pragma unroll
    for (int c = 0; c < 2; ++c) {
        int col = wid * 32 + c * 16 + (lane & 15);
#pragma unroll
        for (int r = 0; r < 4; ++r) {
            int row = prow[r];
            float o = acc[c][r] + bv[c];
            if (FINAL) {
                ((float*)outp)[(size_t)row * D + col] = o;
            } else {
                o = fmaxf(o, 0.f);
                ((f16*)outp)[(size_t)row * D + col] = (f16)o;
                int pk = __builtin_amdgcn_cvt_pk_fp8_f32(o, o, 0, false);
                outp8[(size_t)row * D + col] = (unsigned char)(pk & 0xff);
            }
        }
    }
}

// ---------------- launch ----------------

extern "C" void kernel_launch(void* const* d_in, const int* in_sizes, int n_in,
                              void* d_out, int out_size, void* d_ws, size_t ws_size,
                              hipStream_t stream) {
    const float* x  = (const float*)d_in[0];
    const float* ew = (const float*)d_in[1];
    const float* W_rel[3]  = {(const float*)d_in[2], (const float*)d_in[5], (const float*)d_in[8]};
    const float* W_root[3] = {(const float*)d_in[3], (const float*)d_in[6], (const float*)d_in[9]};
    const float* bias[3]   = {(const float*)d_in[4], (const float*)d_in[7], (const float*)d_in[10]};
    const int* esrc = (const int*)d_in[11];
    const int* edst = (const int*)d_in[12];

    char* ws = (char*)d_ws;
    f16*           bufA16  = (f16*)           (ws);                // 25,600,000 B
    unsigned char* bufA8   = (unsigned char*) (ws + 25600000);     // 12,800,000 B
    f16*           bufB16  = (f16*)           (ws + 38400000);     // 25,600,000 B
    unsigned char* bufB8   = (unsigned char*) (ws + 64000000);     // 12,800,000 B
    unsigned*      csr     = (unsigned*)      (ws + 76800000);     //  6,400,000 B
    int2*          bkt     = (int2*)          (ws + 83200000);     // 16,015,360 B
    int*           row_ptr = (int*)           (ws + 99215360);     //    400,016 B
    int*           bcur    = (int*)           (ws + 99615376);     //      1,564 B
    int*           bbase   = (int*)           (ws + 99616940);     //      1,564 B
    f16*           Bp      = (f16*)           (ws + 99618504);     //    196,608 B
    int*           perm    = (int*)           (ws + 99815112);     //    400,000 B
    int*           ghist   = (int*)           (ws + 100215112);    //        128 B
    int*           gcur    = (int*)           (ws + 100215240);    //        128 B

    // CSR build (bucket-based; reused by all 3 layers)
    hipMemsetAsync(bcur, 0, N_BUCKETS * sizeof(int), stream);
    hipMemsetAsync(ghist, 0, NBINS * sizeof(int), stream);
    bucket_scatter<<<SC_BLOCKS, 256, 0, stream>>>(esrc, edst, ew, bcur, bkt);
    bucket_scan<<<1, 512, 0, stream>>>(bcur, bbase);
    bucket_finalize<<<N_BUCKETS, 256, 0, stream>>>(bcur, bbase, bkt, csr, row_ptr);

    // degree-equalized node permutation (counting sort, width-1 bins)
    degree_hist<<<DS_BLOCKS, 1024, 0, stream>>>(row_ptr, ghist);
    bin_scan<<<1, 32, 0, stream>>>(ghist, gcur);
    degree_place<<<DS_BLOCKS, 1024, 0, stream>>>(row_ptr, gcur, perm);

    // x -> f16 + fp8, weight packs
    cvt_x<<<6250, 256, 0, stream>>>(x, bufA16, bufA8);
    for (int l = 0; l < 3; ++l)
        pack_weights<<<128, 256, 0, stream>>>(W_rel[l], W_root[l], Bp + l * 32768);

    // 3 fused layers: A -> B -> A -> d_out
    fused_layer<0><<<GEMM_GRID, 256, 0, stream>>>(bufA16, bufA8, row_ptr, csr, perm,
                                                  (const f16x8*)(Bp + 0 * 32768),
                                                  bias[0], bufB16, bufB8);
    fused_layer<0><<<GEMM_GRID, 256, 0, stream>>>(bufB16, bufB8, row_ptr, csr, perm,
                                                  (const f16x8*)(Bp + 1 * 32768),
                                                  bias[1], bufA16, bufA8);
    fused_layer<1><<<GEMM_GRID, 256, 0, stream>>>(bufA16, bufA8, row_ptr, csr, perm,
                                                  (const f16x8*)(Bp + 2 * 32768),
                                                  bias[2], d_out, nullptr);
}

// Round 17
// 229.926 us; speedup vs baseline: 1.0508x; 1.0508x over previous
//
#include <hip/hip_runtime.h>

#define N_NODES 100000
#define N_EDGES 1600000
#define D 128
#define GEMM_GRID 6250      // one block per 16-row tile
#define TILE_ROWS 16
#define BK_NODES 256        // nodes per bucket
#define N_BUCKETS 391       // ceil(N_NODES / BK_NODES)
#define BKT_CAP 5120        // per-bucket slot capacity (mean 4092, std 64 -> 16 sigma)
#define SC_BLOCKS 128
#define EPB 12500           // edges per scatter block (N_EDGES / SC_BLOCKS)

typedef _Float16 f16;
typedef _Float16 f16x8 __attribute__((ext_vector_type(8)));
typedef _Float16 f16x2 __attribute__((ext_vector_type(2)));
typedef float f32x2 __attribute__((ext_vector_type(2)));
typedef float f32x4 __attribute__((ext_vector_type(4)));

// bf16 bit pattern of w in [0,1] fits in 15 bits (max 0x3F80 = 1.0), RNE-ish
__device__ __forceinline__ unsigned bf16bits(float x) {
    unsigned u = __float_as_uint(x);
    return ((u + 0x8000u) >> 16) & 0x7fffu;
}

// ---------------- CSR build (bucket-based, no per-node global atomics) ----------------

__global__ __launch_bounds__(256) void bucket_scatter(const int* __restrict__ src,
                                                      const int* __restrict__ dst,
                                                      const float* __restrict__ w,
                                                      int* __restrict__ bcur,
                                                      int2* __restrict__ bkt) {
    __shared__ int hist[N_BUCKETS];
    __shared__ int base[N_BUCKETS];
    int tid = threadIdx.x;
    int v0  = blockIdx.x * (EPB / 4);        // int4-chunk base
    const int4*   dst4 = (const int4*)dst;
    const int4*   src4 = (const int4*)src;
    const float4* w4   = (const float4*)w;

    for (int b = tid; b < N_BUCKETS; b += 256) hist[b] = 0;
    __syncthreads();

    // phase A: count buckets (vectorized dst reads)
    for (int v = tid; v < EPB / 4; v += 256) {
        int4 d = dst4[v0 + v];
        atomicAdd(&hist[d.x >> 8], 1);
        atomicAdd(&hist[d.y >> 8], 1);
        atomicAdd(&hist[d.z >> 8], 1);
        atomicAdd(&hist[d.w >> 8], 1);
    }
    __syncthreads();

    // phase B: reserve within-bucket ranges (bcur starts at 0)
    for (int b = tid; b < N_BUCKETS; b += 256) {
        int c = hist[b];
        base[b] = b * BKT_CAP + ((c > 0) ? atomicAdd(&bcur[b], c) : 0);
        hist[b] = 0;
    }
    __syncthreads();

    // phase C: place edges densely inside reserved ranges (meta = dst<<15 | bf16(w))
    for (int v = tid; v < EPB / 4; v += 256) {
        int4   d = dst4[v0 + v];
        int4   s = src4[v0 + v];
        float4 f = w4[v0 + v];
        {
            int p = base[d.x >> 8] + atomicAdd(&hist[d.x >> 8], 1);
            bkt[p] = make_int2(s.x, (int)(((unsigned)d.x << 15) | bf16bits(f.x)));
        }
        {
            int p = base[d.y >> 8] + atomicAdd(&hist[d.y >> 8], 1);
            bkt[p] = make_int2(s.y, (int)(((unsigned)d.y << 15) | bf16bits(f.y)));
        }
        {
            int p = base[d.z >> 8] + atomicAdd(&hist[d.z >> 8], 1);
            bkt[p] = make_int2(s.z, (int)(((unsigned)d.z << 15) | bf16bits(f.z)));
        }
        {
            int p = base[d.w >> 8] + atomicAdd(&hist[d.w >> 8], 1);
            bkt[p] = make_int2(s.w, (int)(((unsigned)d.w << 15) | bf16bits(f.w)));
        }
    }
}

// exclusive scan over the 391 bucket counts -> bucket CSR bases (one block)
__global__ __launch_bounds__(512) void bucket_scan(const int* __restrict__ bcnt,
                                                   int* __restrict__ bbase) {
    __shared__ int sc[512];
    int tid = threadIdx.x;
    int v = (tid < N_BUCKETS) ? bcnt[tid] : 0;
    sc[tid] = v;
    __syncthreads();
    for (int off = 1; off < 512; off <<= 1) {
        int t = (tid >= off) ? sc[tid - off] : 0;
        __syncthreads();
        sc[tid] += t;
        __syncthreads();
    }
    if (tid < N_BUCKETS) bbase[tid] = sc[tid] - v;
}

// pass 2: one block per bucket. LDS node histogram + block scan -> row_ptr AND
// final csr placement. csr[p] = (src << 15) | bf16(w).
__global__ __launch_bounds__(256) void bucket_finalize(const int* __restrict__ bcnt,
                                                       const int* __restrict__ bbase,
                                                       const int2* __restrict__ bkt,
                                                       unsigned* __restrict__ csr,
                                                       int* __restrict__ row_ptr) {
    __shared__ int ncnt[BK_NODES];
    __shared__ int noff[BK_NODES];
    __shared__ int sc[BK_NODES];
    int tid   = threadIdx.x;
    int b     = blockIdx.x;
    int node0 = b * BK_NODES;
    int cnt   = bcnt[b];
    int base  = bbase[b];
    int e0    = b * BKT_CAP;

    ncnt[tid] = 0;
    __syncthreads();
    for (int i = tid; i < cnt; i += 256) {
        int local = (int)((unsigned)bkt[e0 + i].y >> 15) - node0;
        atomicAdd(&ncnt[local], 1);
    }
    __syncthreads();
    int s = ncnt[tid];
    sc[tid] = s;
    __syncthreads();
    for (int off = 1; off < 256; off <<= 1) {
        int t = (tid >= off) ? sc[tid - off] : 0;
        __syncthreads();
        sc[tid] += t;
        __syncthreads();
    }
    noff[tid] = sc[tid] - s;
    ncnt[tid] = 0;   // reuse as placement cursor
    {
        int nN = N_NODES - node0; if (nN > BK_NODES) nN = BK_NODES;
        if (tid < nN) row_ptr[node0 + tid] = base + noff[tid];
        if (b == N_BUCKETS - 1 && tid == 0) row_ptr[N_NODES] = N_EDGES;
    }
    __syncthreads();
    for (int i = tid; i < cnt; i += 256) {
        int2 t = bkt[e0 + i];
        unsigned meta = (unsigned)t.y;
        int local = (int)(meta >> 15) - node0;
        int p = base + noff[local] + atomicAdd(&ncnt[local], 1);
        csr[p] = ((unsigned)t.x << 15) | (meta & 0x7fffu);
    }
}

// ---------------- fp32 -> f16 + fp8 convert (x only, once) ----------------

__global__ __launch_bounds__(256) void cvt_x(const float* __restrict__ in,
                                             f16* __restrict__ out16,
                                             unsigned char* __restrict__ out8) {
    int i = blockIdx.x * 256 + threadIdx.x;   // grid 6250: 8 elems/thread
    const float4* in4 = (const float4*)in;
    float4 a = in4[i * 2], b = in4[i * 2 + 1];
    f16x8 v;
    v[0] = (f16)a.x; v[1] = (f16)a.y; v[2] = (f16)a.z; v[3] = (f16)a.w;
    v[4] = (f16)b.x; v[5] = (f16)b.y; v[6] = (f16)b.z; v[7] = (f16)b.w;
    ((f16x8*)out16)[i] = v;
    uint2 p8;
    int r = __builtin_amdgcn_cvt_pk_fp8_f32(a.x, a.y, 0, false);
    r     = __builtin_amdgcn_cvt_pk_fp8_f32(a.z, a.w, r, true);
    p8.x = (unsigned)r;
    r     = __builtin_amdgcn_cvt_pk_fp8_f32(b.x, b.y, 0, false);
    r     = __builtin_amdgcn_cvt_pk_fp8_f32(b.z, b.w, r, true);
    p8.y = (unsigned)r;
    ((uint2*)out8)[i] = p8;
}

// ---------------- weight pack: B-fragment layout, f16 ----------------
// Bp element ((ks*8 + ct)*64 + lane)*8 + e = W[j][k] with
// j = ct*16 + (lane&15), k = ks*32 + (lane>>4)*8 + e  (k<128 -> Wrel, else Wroot)

__global__ __launch_bounds__(256) void pack_weights(const float* __restrict__ Wrel,
                                                    const float* __restrict__ Wroot,
                                                    f16* __restrict__ Bp) {
    int idx = blockIdx.x * 256 + threadIdx.x;   // 32768 total -> 128 blocks
    int e = idx & 7, lane = (idx >> 3) & 63, ct = (idx >> 9) & 7, ks = idx >> 12;
    int j = ct * 16 + (lane & 15);
    int k = ks * 32 + (lane >> 4) * 8 + e;
    float w = (k < D) ? Wrel[j * D + k] : Wroot[j * D + (k - D)];
    Bp[idx] = (f16)w;
}

// ---------------- FUSED layer: quad-per-node fp8 aggregate + MFMA GEMM ----------------
// 16-row tiles, 6250 blocks. Phase 1: each 16-lane QUAD owns ONE node; lane
// covers 8 fp8 channels (8 B). 16-DEEP batches: all (typically) of a node's
// edges issued before any consume -> 1-2 miss round-trips per node instead of
// 2-3 (r10's proven issue pattern in quad geometry). Clamped tail batch
// (broadcast-cheap, w=0). Phase 2: wave wid computes 16 rows x cols
// [wid*32,+32), B streamed from L2.
// FINAL=0: f16 out + fp8 out + ReLU.  FINAL=1: fp32 out only.

#define FMA8(CWV)                                                              \
    {                                                                          \
        float w = __uint_as_float(((CWV) & 0x7fffu) << 16);                    \
        f32x2 c0 = __builtin_amdgcn_cvt_pk_f32_fp8((int)rv[j].x, false);       \
        f32x2 c1 = __builtin_amdgcn_cvt_pk_f32_fp8((int)rv[j].x, true);        \
        f32x2 c2 = __builtin_amdgcn_cvt_pk_f32_fp8((int)rv[j].y, false);       \
        f32x2 c3 = __builtin_amdgcn_cvt_pk_f32_fp8((int)rv[j].y, true);        \
        a0 = fmaf(w, c0.x, a0); a1 = fmaf(w, c0.y, a1);                        \
        a2 = fmaf(w, c1.x, a2); a3 = fmaf(w, c1.y, a3);                        \
        a4 = fmaf(w, c2.x, a4); a5 = fmaf(w, c2.y, a5);                        \
        a6 = fmaf(w, c3.x, a6); a7 = fmaf(w, c3.y, a7);                        \
    }

template <int FINAL>
__global__ __launch_bounds__(256) void fused_layer(const f16* __restrict__ h,
                                                   const unsigned char* __restrict__ h8,
                                                   const int* __restrict__ row_ptr,
                                                   const unsigned* __restrict__ csr,
                                                   const f16x8* __restrict__ Bp,
                                                   const float* __restrict__ bias,
                                                   void* __restrict__ outp,
                                                   unsigned char* __restrict__ outp8) {
    __shared__ f16 sA[TILE_ROWS * 256];   // 8 KB: [row][k] k<128 agg, k>=128 h (XOR swz)
    int tid  = threadIdx.x;
    int lane = tid & 63;
    int wid  = tid >> 6;
    int node0 = blockIdx.x * TILE_ROWS;
    const uint4* h16 = (const uint4*)h;

    // ---- phase 1a: quad-per-node aggregation (fp8 rows, 8 B/lane), 16-deep ----
    int quad = lane >> 4;             // 0..3
    int ql   = lane & 15;
    unsigned qoff = (unsigned)ql * 8u;   // byte offset into 128B fp8 row

    {
        int row  = wid * 4 + quad;    // 0..15: one node per quad
        int node = node0 + row;
        int beg = row_ptr[node], end = row_ptr[node + 1];

        float a0 = 0.f, a1 = 0.f, a2 = 0.f, a3 = 0.f;
        float a4 = 0.f, a5 = 0.f, a6 = 0.f, a7 = 0.f;

        int e = beg;
        while (e + 16 <= end) {       // full 16-batch: all edges in flight at once
            unsigned cw[16];
#pragma unroll
            for (int j = 0; j < 16; ++j) cw[j] = csr[e + j];   // quad-broadcast lines
            uint2 rv[16];
            __builtin_amdgcn_sched_barrier(0);
#pragma unroll
            for (int j = 0; j < 16; ++j) {
                unsigned off = ((cw[j] >> 8) & 0xFFFFFF80u) | qoff;  // src*128 | ql*8
                rv[j] = *(const uint2*)(h8 + off);                   // 4 edges / wave inst
            }
            __builtin_amdgcn_sched_barrier(0);   // keep all 16 gathers in flight
#pragma unroll
            for (int j = 0; j < 16; ++j) FMA8(cw[j]);
            e += 16;
        }
        if (e < end) {   // clamped tail 16-batch (dup-addr gathers broadcast, w=0)
            int rem = end - e;                   // 1..15
            int em1 = end - 1;
            unsigned sm[16];
#pragma unroll
            for (int j = 0; j < 16; ++j) {
                int idx = e + j; idx = idx < em1 ? idx : em1;
                unsigned c = csr[idx];
                sm[j] = (j < rem) ? c : 0u;
            }
            uint2 rv[16];
            __builtin_amdgcn_sched_barrier(0);
#pragma unroll
            for (int j = 0; j < 16; ++j) {
                unsigned off = ((sm[j] >> 8) & 0xFFFFFF80u) | qoff;
                rv[j] = *(const uint2*)(h8 + off);
            }
            __builtin_amdgcn_sched_barrier(0);
#pragma unroll
            for (int j = 0; j < 16; ++j) FMA8(sm[j]);
        }
        f16x8 ov;
        ov[0] = (f16)a0; ov[1] = (f16)a1; ov[2] = (f16)a2; ov[3] = (f16)a3;
        ov[4] = (f16)a4; ov[5] = (f16)a5; ov[6] = (f16)a6; ov[7] = (f16)a7;
        int o = (row * 256 + ql * 8) ^ ((row & 7) << 3);
        *(f16x8*)&sA[o] = ov;
    }

    // ---- phase 1b: stage f16 h rows into cols 128-255 (256 uint4 chunks) ----
    {
        int r = tid >> 4, c8 = (tid & 15) + 16;
        int o = (r * 256 + c8 * 8) ^ ((r & 7) << 3);
        *(uint4*)&sA[o] = h16[(size_t)(node0 + r) * 16 + (c8 - 16)];
    }
    __syncthreads();

    // ---- phase 2: MFMA — wave wid: all 16 rows x cols [wid*32,+32) ----
    float bv[2];
#pragma unroll
    for (int c = 0; c < 2; ++c) bv[c] = bias[wid * 32 + c * 16 + (lane & 15)];

    f32x4 acc[2] = {f32x4{0,0,0,0}, f32x4{0,0,0,0}};
    int arow = lane & 15;
    int kg   = (lane >> 4) * 8;

    f16x8 b0 = Bp[(0 * 8 + wid * 2 + 0) * 64 + lane];
    f16x8 b1 = Bp[(0 * 8 + wid * 2 + 1) * 64 + lane];
#pragma unroll 1
    for (int ks = 0; ks < 8; ++ks) {
        f16x8 n0, n1;
        if (ks < 7) {   // 1-deep pipeline: issue next B-frags before MFMA
            n0 = Bp[((ks + 1) * 8 + wid * 2 + 0) * 64 + lane];
            n1 = Bp[((ks + 1) * 8 + wid * 2 + 1) * 64 + lane];
        }
        int o = (arow * 256 + ks * 32 + kg) ^ ((arow & 7) << 3);
        f16x8 afrag = *(const f16x8*)&sA[o];
        acc[0] = __builtin_amdgcn_mfma_f32_16x16x32_f16(afrag, b0, acc[0], 0, 0, 0);
        acc[1] = __builtin_amdgcn_mfma_f32_16x16x32_f16(afrag, b1, acc[1], 0, 0, 0);
        b0 = n0; b1 = n1;
    }

    // epilogue: bias (+relu), store  (C/D map: col=lane&15, row=(lane>>4)*4+r)
#pragma unroll
    for (int c = 0; c < 2; ++c) {
        int col = wid * 32 + c * 16 + (lane & 15);
#pragma unroll
        for (int r = 0; r < 4; ++r) {
            int row = node0 + (lane >> 4) * 4 + r;
            float o = acc[c][r] + bv[c];
            if (FINAL) {
                ((float*)outp)[(size_t)row * D + col] = o;
            } else {
                o = fmaxf(o, 0.f);
                ((f16*)outp)[(size_t)row * D + col] = (f16)o;
                int pk = __builtin_amdgcn_cvt_pk_fp8_f32(o, o, 0, false);
                outp8[(size_t)row * D + col] = (unsigned char)(pk & 0xff);
            }
        }
    }
}

// ---------------- launch ----------------

extern "C" void kernel_launch(void* const* d_in, const int* in_sizes, int n_in,
                              void* d_out, int out_size, void* d_ws, size_t ws_size,
                              hipStream_t stream) {
    const float* x  = (const float*)d_in[0];
    const float* ew = (const float*)d_in[1];
    const float* W_rel[3]  = {(const float*)d_in[2], (const float*)d_in[5], (const float*)d_in[8]};
    const float* W_root[3] = {(const float*)d_in[3], (const float*)d_in[6], (const float*)d_in[9]};
    const float* bias[3]   = {(const float*)d_in[4], (const float*)d_in[7], (const float*)d_in[10]};
    const int* esrc = (const int*)d_in[11];
    const int* edst = (const int*)d_in[12];

    char* ws = (char*)d_ws;
    f16*           bufA16  = (f16*)           (ws);               // 25,600,000 B
    unsigned char* bufA8   = (unsigned char*) (ws + 25600000);    // 12,800,000 B
    f16*           bufB16  = (f16*)           (ws + 38400000);    // 25,600,000 B
    unsigned char* bufB8   = (unsigned char*) (ws + 64000000);    // 12,800,000 B
    unsigned*      csr     = (unsigned*)      (ws + 76800000);    //  6,400,000 B
    int2*          bkt     = (int2*)          (ws + 83200000);    // 16,015,360 B
    int*           row_ptr = (int*)           (ws + 99215360);    //    400,016 B
    int*           bcur    = (int*)           (ws + 99615376);    //      1,564 B
    int*           bbase   = (int*)           (ws + 99616940);    //      1,564 B
    f16*           Bp      = (f16*)           (ws + 99618504);    //    196,608 B

    // CSR build (bucket-based; reused by all 3 layers)
    hipMemsetAsync(bcur, 0, N_BUCKETS * sizeof(int), stream);
    bucket_scatter<<<SC_BLOCKS, 256, 0, stream>>>(esrc, edst, ew, bcur, bkt);
    bucket_scan<<<1, 512, 0, stream>>>(bcur, bbase);
    bucket_finalize<<<N_BUCKETS, 256, 0, stream>>>(bcur, bbase, bkt, csr, row_ptr);

    // x -> f16 + fp8, weight packs
    cvt_x<<<6250, 256, 0, stream>>>(x, bufA16, bufA8);
    for (int l = 0; l < 3; ++l)
        pack_weights<<<128, 256, 0, stream>>>(W_rel[l], W_root[l], Bp + l * 32768);

    // 3 fused layers: A -> B -> A -> d_out
    fused_layer<0><<<GEMM_GRID, 256, 0, stream>>>(bufA16, bufA8, row_ptr, csr,
                                                  (const f16x8*)(Bp + 0 * 32768),
                                                  bias[0], bufB16, bufB8);
    fused_layer<0><<<GEMM_GRID, 256, 0, stream>>>(bufB16, bufB8, row_ptr, csr,
                                                  (const f16x8*)(Bp + 1 * 32768),
                                                  bias[1], bufA16, bufA8);
    fused_layer<1><<<GEMM_GRID, 256, 0, stream>>>(bufA16, bufA8, row_ptr, csr,
                                                  (const f16x8*)(Bp + 2 * 32768),
                                                  bias[2], d_out, nullptr);
}

// Round 18
// 213.953 us; speedup vs baseline: 1.1293x; 1.0747x over previous
//
#include <hip/hip_runtime.h>

#define N_NODES 100000
#define N_EDGES 1600000
#define D 128
#define GEMM_GRID 6250      // one block per 16-row tile
#define TILE_ROWS 16
#define BK_NODES 256        // nodes per bucket
#define N_BUCKETS 391       // ceil(N_NODES / BK_NODES)
#define BKT_CAP 5120        // per-bucket slot capacity (mean 4092, std 64 -> 16 sigma)
#define SC_BLOCKS 128
#define EPB 12500           // edges per scatter block (N_EDGES / SC_BLOCKS)

typedef _Float16 f16;
typedef _Float16 f16x8 __attribute__((ext_vector_type(8)));
typedef _Float16 f16x2 __attribute__((ext_vector_type(2)));
typedef float f32x2 __attribute__((ext_vector_type(2)));
typedef float f32x4 __attribute__((ext_vector_type(4)));

// bf16 bit pattern of w in [0,1] fits in 15 bits (max 0x3F80 = 1.0), RNE-ish
__device__ __forceinline__ unsigned bf16bits(float x) {
    unsigned u = __float_as_uint(x);
    return ((u + 0x8000u) >> 16) & 0x7fffu;
}

// ---------------- CSR build (bucket-based, no per-node global atomics) ----------------

__global__ __launch_bounds__(256) void bucket_scatter(const int* __restrict__ src,
                                                      const int* __restrict__ dst,
                                                      const float* __restrict__ w,
                                                      int* __restrict__ bcur,
                                                      int2* __restrict__ bkt) {
    __shared__ int hist[N_BUCKETS];
    __shared__ int base[N_BUCKETS];
    int tid = threadIdx.x;
    int v0  = blockIdx.x * (EPB / 4);        // int4-chunk base
    const int4*   dst4 = (const int4*)dst;
    const int4*   src4 = (const int4*)src;
    const float4* w4   = (const float4*)w;

    for (int b = tid; b < N_BUCKETS; b += 256) hist[b] = 0;
    __syncthreads();

    // phase A: count buckets; cache dst in registers for phase C (static idx)
    int4 dc[13];
#pragma unroll
    for (int it = 0; it < 13; ++it) {
        int v = tid + it * 256;
        if (v < EPB / 4) {
            int4 d = dst4[v0 + v];
            dc[it] = d;
            atomicAdd(&hist[d.x >> 8], 1);
            atomicAdd(&hist[d.y >> 8], 1);
            atomicAdd(&hist[d.z >> 8], 1);
            atomicAdd(&hist[d.w >> 8], 1);
        }
    }
    __syncthreads();

    // phase B: reserve within-bucket ranges (bcur starts at 0)
    for (int b = tid; b < N_BUCKETS; b += 256) {
        int c = hist[b];
        base[b] = b * BKT_CAP + ((c > 0) ? atomicAdd(&bcur[b], c) : 0);
        hist[b] = 0;
    }
    __syncthreads();

    // phase C: place edges densely inside reserved ranges (meta = dst<<15 | bf16(w))
#pragma unroll
    for (int it = 0; it < 13; ++it) {
        int v = tid + it * 256;
        if (v < EPB / 4) {
            int4   d = dc[it];
            int4   s = src4[v0 + v];
            float4 f = w4[v0 + v];
            {
                int p = base[d.x >> 8] + atomicAdd(&hist[d.x >> 8], 1);
                bkt[p] = make_int2(s.x, (int)(((unsigned)d.x << 15) | bf16bits(f.x)));
            }
            {
                int p = base[d.y >> 8] + atomicAdd(&hist[d.y >> 8], 1);
                bkt[p] = make_int2(s.y, (int)(((unsigned)d.y << 15) | bf16bits(f.y)));
            }
            {
                int p = base[d.z >> 8] + atomicAdd(&hist[d.z >> 8], 1);
                bkt[p] = make_int2(s.z, (int)(((unsigned)d.z << 15) | bf16bits(f.z)));
            }
            {
                int p = base[d.w >> 8] + atomicAdd(&hist[d.w >> 8], 1);
                bkt[p] = make_int2(s.w, (int)(((unsigned)d.w << 15) | bf16bits(f.w)));
            }
        }
    }
}

// pass 2: one block per bucket. Internal base reduction (replaces bucket_scan),
// LDS node histogram + block scan -> row_ptr AND final csr placement.
// csr[p] = (src << 15) | bf16(w).
__global__ __launch_bounds__(256) void bucket_finalize(const int* __restrict__ bcnt,
                                                       const int2* __restrict__ bkt,
                                                       unsigned* __restrict__ csr,
                                                       int* __restrict__ row_ptr) {
    __shared__ int ncnt[BK_NODES];
    __shared__ int noff[BK_NODES];
    __shared__ int sc[BK_NODES];
    int tid   = threadIdx.x;
    int b     = blockIdx.x;
    int node0 = b * BK_NODES;
    int cnt   = bcnt[b];
    int e0    = b * BKT_CAP;

    // base = sum of bcnt[0..b) — block reduction (L2-hot, 391 ints max)
    int part = 0;
    for (int i = tid; i < b; i += 256) part += bcnt[i];
    sc[tid] = part;
    __syncthreads();
    for (int off = 128; off > 0; off >>= 1) {
        if (tid < off) sc[tid] += sc[tid + off];
        __syncthreads();
    }
    int base = sc[0];
    __syncthreads();

    ncnt[tid] = 0;
    __syncthreads();
    for (int i = tid; i < cnt; i += 256) {
        int local = (int)((unsigned)bkt[e0 + i].y >> 15) - node0;
        atomicAdd(&ncnt[local], 1);
    }
    __syncthreads();
    int s = ncnt[tid];
    sc[tid] = s;
    __syncthreads();
    for (int off = 1; off < 256; off <<= 1) {
        int t = (tid >= off) ? sc[tid - off] : 0;
        __syncthreads();
        sc[tid] += t;
        __syncthreads();
    }
    noff[tid] = sc[tid] - s;
    ncnt[tid] = 0;   // reuse as placement cursor
    {
        int nN = N_NODES - node0; if (nN > BK_NODES) nN = BK_NODES;
        if (tid < nN) row_ptr[node0 + tid] = base + noff[tid];
        if (b == N_BUCKETS - 1 && tid == 0) row_ptr[N_NODES] = N_EDGES;
    }
    __syncthreads();
    for (int i = tid; i < cnt; i += 256) {
        int2 t = bkt[e0 + i];
        unsigned meta = (unsigned)t.y;
        int local = (int)(meta >> 15) - node0;
        int p = base + noff[local] + atomicAdd(&ncnt[local], 1);
        csr[p] = ((unsigned)t.x << 15) | (meta & 0x7fffu);
    }
}

// ---------------- fp32 -> f16 + fp8 convert (x only, once) ----------------

__global__ __launch_bounds__(256) void cvt_x(const float* __restrict__ in,
                                             f16* __restrict__ out16,
                                             unsigned char* __restrict__ out8) {
    int i = blockIdx.x * 256 + threadIdx.x;   // grid 6250: 8 elems/thread
    const float4* in4 = (const float4*)in;
    float4 a = in4[i * 2], b = in4[i * 2 + 1];
    f16x8 v;
    v[0] = (f16)a.x; v[1] = (f16)a.y; v[2] = (f16)a.z; v[3] = (f16)a.w;
    v[4] = (f16)b.x; v[5] = (f16)b.y; v[6] = (f16)b.z; v[7] = (f16)b.w;
    ((f16x8*)out16)[i] = v;
    uint2 p8;
    int r = __builtin_amdgcn_cvt_pk_fp8_f32(a.x, a.y, 0, false);
    r     = __builtin_amdgcn_cvt_pk_fp8_f32(a.z, a.w, r, true);
    p8.x = (unsigned)r;
    r     = __builtin_amdgcn_cvt_pk_fp8_f32(b.x, b.y, 0, false);
    r     = __builtin_amdgcn_cvt_pk_fp8_f32(b.z, b.w, r, true);
    p8.y = (unsigned)r;
    ((uint2*)out8)[i] = p8;
}

// ---------------- weight pack: B-fragment layout, f16 ----------------
// Bp element ((ks*8 + ct)*64 + lane)*8 + e = W[j][k] with
// j = ct*16 + (lane&15), k = ks*32 + (lane>>4)*8 + e  (k<128 -> Wrel, else Wroot)

__global__ __launch_bounds__(256) void pack_weights(const float* __restrict__ Wrel,
                                                    const float* __restrict__ Wroot,
                                                    f16* __restrict__ Bp) {
    int idx = blockIdx.x * 256 + threadIdx.x;   // 32768 total -> 128 blocks
    int e = idx & 7, lane = (idx >> 3) & 63, ct = (idx >> 9) & 7, ks = idx >> 12;
    int j = ct * 16 + (lane & 15);
    int k = ks * 32 + (lane >> 4) * 8 + e;
    float w = (k < D) ? Wrel[j * D + k] : Wroot[j * D + (k - D)];
    Bp[idx] = (f16)w;
}

// ---------------- FUSED layer: quad-per-node fp8 aggregate + MFMA GEMM ----------------
// r15 structure (measured best: 55.9 us/layer). 16-row tiles, 6250 blocks.
// Phase 1: each 16-lane QUAD owns ONE node; lane covers 8 fp8 channels (8 B).
// 8-batch unroll, csr prefetch, f32 accumulate, f16x8 into swizzled LDS.
// Phase 2: wave wid computes all 16 rows x cols [wid*32,+32), B streamed.
// FINAL=0: f16 out + fp8 out + ReLU.  FINAL=1: fp32 out only.

#define FMA8(CWV)                                                              \
    {                                                                          \
        float w = __uint_as_float(((CWV) & 0x7fffu) << 16);                    \
        f32x2 c0 = __builtin_amdgcn_cvt_pk_f32_fp8((int)rv[j].x, false);       \
        f32x2 c1 = __builtin_amdgcn_cvt_pk_f32_fp8((int)rv[j].x, true);        \
        f32x2 c2 = __builtin_amdgcn_cvt_pk_f32_fp8((int)rv[j].y, false);       \
        f32x2 c3 = __builtin_amdgcn_cvt_pk_f32_fp8((int)rv[j].y, true);        \
        a0 = fmaf(w, c0.x, a0); a1 = fmaf(w, c0.y, a1);                        \
        a2 = fmaf(w, c1.x, a2); a3 = fmaf(w, c1.y, a3);                        \
        a4 = fmaf(w, c2.x, a4); a5 = fmaf(w, c2.y, a5);                        \
        a6 = fmaf(w, c3.x, a6); a7 = fmaf(w, c3.y, a7);                        \
    }

template <int FINAL>
__global__ __launch_bounds__(256) void fused_layer(const f16* __restrict__ h,
                                                   const unsigned char* __restrict__ h8,
                                                   const int* __restrict__ row_ptr,
                                                   const unsigned* __restrict__ csr,
                                                   const f16x8* __restrict__ Bp,
                                                   const float* __restrict__ bias,
                                                   void* __restrict__ outp,
                                                   unsigned char* __restrict__ outp8) {
    __shared__ f16 sA[TILE_ROWS * 256];   // 8 KB: [row][k] k<128 agg, k>=128 h (XOR swz)
    int tid  = threadIdx.x;
    int lane = tid & 63;
    int wid  = tid >> 6;
    int node0 = blockIdx.x * TILE_ROWS;
    const uint4* h16 = (const uint4*)h;

    // ---- phase 1a: quad-per-node aggregation (fp8 rows, 8 B/lane) ----
    int quad = lane >> 4;             // 0..3
    int ql   = lane & 15;
    unsigned qoff = (unsigned)ql * 8u;   // byte offset into 128B fp8 row

    {
        int row  = wid * 4 + quad;    // 0..15: one node per quad
        int node = node0 + row;
        int beg = row_ptr[node], end = row_ptr[node + 1];

        float a0 = 0.f, a1 = 0.f, a2 = 0.f, a3 = 0.f;
        float a4 = 0.f, a5 = 0.f, a6 = 0.f, a7 = 0.f;

        int e = beg;
        unsigned cw[8];
        if (e + 8 <= end) {
#pragma unroll
            for (int j = 0; j < 8; ++j) cw[j] = csr[e + j];   // quad-broadcast lines
        }
        while (e + 8 <= end) {
            uint2 rv[8];
            __builtin_amdgcn_sched_barrier(0);
#pragma unroll
            for (int j = 0; j < 8; ++j) {
                unsigned off = ((cw[j] >> 8) & 0xFFFFFF80u) | qoff;  // (src)*128 | ql*8
                rv[j] = *(const uint2*)(h8 + off);                   // 4 edges / wave inst
            }
            unsigned cwn[8];
            bool more = (e + 16 <= end);
            if (more) {   // prefetch next batch's csr words under the gathers
#pragma unroll
                for (int j = 0; j < 8; ++j) cwn[j] = csr[e + 8 + j];
            }
            __builtin_amdgcn_sched_barrier(0);
#pragma unroll
            for (int j = 0; j < 8; ++j) FMA8(cw[j]);
            if (more) {
#pragma unroll
                for (int j = 0; j < 8; ++j) cw[j] = cwn[j];
            }
            e += 8;
        }
        if (e < end) {   // clamped tail batch (1..7 edges), w=0 for dead j
            int rem = end - e;
            int em1 = end - 1;
            unsigned sm[8];
            uint2 rv[8];
#pragma unroll
            for (int j = 0; j < 8; ++j) {
                int idx = e + j; idx = idx < em1 ? idx : em1;
                unsigned c = csr[idx];
                sm[j] = (j < rem) ? c : 0u;
            }
            __builtin_amdgcn_sched_barrier(0);
#pragma unroll
            for (int j = 0; j < 8; ++j) {
                unsigned off = ((sm[j] >> 8) & 0xFFFFFF80u) | qoff;
                rv[j] = *(const uint2*)(h8 + off);
            }
            __builtin_amdgcn_sched_barrier(0);
#pragma unroll
            for (int j = 0; j < 8; ++j) FMA8(sm[j]);
        }
        f16x8 ov;
        ov[0] = (f16)a0; ov[1] = (f16)a1; ov[2] = (f16)a2; ov[3] = (f16)a3;
        ov[4] = (f16)a4; ov[5] = (f16)a5; ov[6] = (f16)a6; ov[7] = (f16)a7;
        int o = (row * 256 + ql * 8) ^ ((row & 7) << 3);
        *(f16x8*)&sA[o] = ov;
    }

    // ---- phase 1b: stage f16 h rows into cols 128-255 (256 uint4 chunks) ----
    {
        int r = tid >> 4, c8 = (tid & 15) + 16;
        int o = (r * 256 + c8 * 8) ^ ((r & 7) << 3);
        *(uint4*)&sA[o] = h16[(size_t)(node0 + r) * 16 + (c8 - 16)];
    }
    __syncthreads();

    // ---- phase 2: MFMA — wave wid: all 16 rows x cols [wid*32,+32) ----
    float bv[2];
#pragma unroll
    for (int c = 0; c < 2; ++c) bv[c] = bias[wid * 32 + c * 16 + (lane & 15)];

    f32x4 acc[2] = {f32x4{0,0,0,0}, f32x4{0,0,0,0}};
    int arow = lane & 15;
    int kg   = (lane >> 4) * 8;

    f16x8 b0 = Bp[(0 * 8 + wid * 2 + 0) * 64 + lane];
    f16x8 b1 = Bp[(0 * 8 + wid * 2 + 1) * 64 + lane];
#pragma unroll 1
    for (int ks = 0; ks < 8; ++ks) {
        f16x8 n0, n1;
        if (ks < 7) {   // 1-deep pipeline: issue next B-frags before MFMA
            n0 = Bp[((ks + 1) * 8 + wid * 2 + 0) * 64 + lane];
            n1 = Bp[((ks + 1) * 8 + wid * 2 + 1) * 64 + lane];
        }
        int o = (arow * 256 + ks * 32 + kg) ^ ((arow & 7) << 3);
        f16x8 afrag = *(const f16x8*)&sA[o];
        acc[0] = __builtin_amdgcn_mfma_f32_16x16x32_f16(afrag, b0, acc[0], 0, 0, 0);
        acc[1] = __builtin_amdgcn_mfma_f32_16x16x32_f16(afrag, b1, acc[1], 0, 0, 0);
        b0 = n0; b1 = n1;
    }

    // epilogue: bias (+relu), store  (C/D map: col=lane&15, row=(lane>>4)*4+r)
#pragma unroll
    for (int c = 0; c < 2; ++c) {
        int col = wid * 32 + c * 16 + (lane & 15);
#pragma unroll
        for (int r = 0; r < 4; ++r) {
            int row = node0 + (lane >> 4) * 4 + r;
            float o = acc[c][r] + bv[c];
            if (FINAL) {
                ((float*)outp)[(size_t)row * D + col] = o;
            } else {
                o = fmaxf(o, 0.f);
                ((f16*)outp)[(size_t)row * D + col] = (f16)o;
                int pk = __builtin_amdgcn_cvt_pk_fp8_f32(o, o, 0, false);
                outp8[(size_t)row * D + col] = (unsigned char)(pk & 0xff);
            }
        }
    }
}

// ---------------- launch ----------------

extern "C" void kernel_launch(void* const* d_in, const int* in_sizes, int n_in,
                              void* d_out, int out_size, void* d_ws, size_t ws_size,
                              hipStream_t stream) {
    const float* x  = (const float*)d_in[0];
    const float* ew = (const float*)d_in[1];
    const float* W_rel[3]  = {(const float*)d_in[2], (const float*)d_in[5], (const float*)d_in[8]};
    const float* W_root[3] = {(const float*)d_in[3], (const float*)d_in[6], (const float*)d_in[9]};
    const float* bias[3]   = {(const float*)d_in[4], (const float*)d_in[7], (const float*)d_in[10]};
    const int* esrc = (const int*)d_in[11];
    const int* edst = (const int*)d_in[12];

    char* ws = (char*)d_ws;
    f16*           bufA16  = (f16*)           (ws);               // 25,600,000 B
    unsigned char* bufA8   = (unsigned char*) (ws + 25600000);    // 12,800,000 B
    f16*           bufB16  = (f16*)           (ws + 38400000);    // 25,600,000 B
    unsigned char* bufB8   = (unsigned char*) (ws + 64000000);    // 12,800,000 B
    unsigned*      csr     = (unsigned*)      (ws + 76800000);    //  6,400,000 B
    int2*          bkt     = (int2*)          (ws + 83200000);    // 16,015,360 B
    int*           row_ptr = (int*)           (ws + 99215360);    //    400,016 B
    int*           bcur    = (int*)           (ws + 99615376);    //      1,564 B
    f16*           Bp      = (f16*)           (ws + 99616940);    //    196,608 B

    // CSR build (bucket-based; reused by all 3 layers)
    hipMemsetAsync(bcur, 0, N_BUCKETS * sizeof(int), stream);
    bucket_scatter<<<SC_BLOCKS, 256, 0, stream>>>(esrc, edst, ew, bcur, bkt);
    bucket_finalize<<<N_BUCKETS, 256, 0, stream>>>(bcur, bkt, csr, row_ptr);

    // x -> f16 + fp8, weight packs
    cvt_x<<<6250, 256, 0, stream>>>(x, bufA16, bufA8);
    for (int l = 0; l < 3; ++l)
        pack_weights<<<128, 256, 0, stream>>>(W_rel[l], W_root[l], Bp + l * 32768);

    // 3 fused layers: A -> B -> A -> d_out
    fused_layer<0><<<GEMM_GRID, 256, 0, stream>>>(bufA16, bufA8, row_ptr, csr,
                                                  (const f16x8*)(Bp + 0 * 32768),
                                                  bias[0], bufB16, bufB8);
    fused_layer<0><<<GEMM_GRID, 256, 0, stream>>>(bufB16, bufB8, row_ptr, csr,
                                                  (const f16x8*)(Bp + 1 * 32768),
                                                  bias[1], bufA16, bufA8);
    fused_layer<1><<<GEMM_GRID, 256, 0, stream>>>(bufA16, bufA8, row_ptr, csr,
                                                  (const f16x8*)(Bp + 2 * 32768),
                                                  bias[2], d_out, nullptr);
}